// Round 2
// baseline (1785.998 us; speedup 1.0000x reference)
//
#include <hip/hip_runtime.h>
#include <hip/hip_bf16.h>
#include <math.h>

#define NGRAPH 128
#define NPG_   512
#define NN     (NGRAPH*NPG_)     // 65536 nodes
#define EPG    504
#define ETOT   (NGRAPH*EPG)      // 64512 real edges
#define HEADS  8
#define FDIM   512
#define NEG    0.2f

typedef __hip_bfloat16 bf16;

static __device__ __forceinline__ float to_f(float v){ return v; }
static __device__ __forceinline__ float to_f(bf16 v){ return __bfloat162float(v); }
static __device__ __forceinline__ void st_f(float* p, float v){ *p = v; }
static __device__ __forceinline__ void st_f(bf16* p, float v){ *p = __float2bfloat16(v); }

// ---------------- workspace guard ----------------
__global__ void k_sentinel(float* out, int n){
  int i = blockIdx.x*blockDim.x + threadIdx.x;
  if (i < n) out[i] = 12345.0f;
}

// ---------------- CSR build ----------------
__global__ void k_zero(int* __restrict__ deg, int* __restrict__ cursor, float* __restrict__ ssum){
  int i = blockIdx.x*blockDim.x + threadIdx.x;
  if (i < NN){ deg[i]=0; cursor[i]=0; ssum[i]=0.f; }
}

__global__ void k_count(const int* __restrict__ ei, const float* __restrict__ ea,
                        int* __restrict__ deg, float* __restrict__ ssum){
  int e = blockIdx.x*blockDim.x + threadIdx.x;
  if (e >= ETOT) return;
  int g = e / EPG;
  int dst = ei[e*2+1] + g*NPG_;
  atomicAdd(&deg[dst], 1);
  atomicAdd(&ssum[dst], ea[e]);
}

__global__ __launch_bounds__(1024) void k_scan1(const int* __restrict__ deg,
                                                int* __restrict__ incl, int* __restrict__ bsum){
  __shared__ int tmp[1024];
  int t = threadIdx.x;
  int i = blockIdx.x*1024 + t;
  tmp[t] = deg[i];
  __syncthreads();
  for (int o=1;o<1024;o<<=1){
    int v = (t>=o) ? tmp[t-o] : 0;
    __syncthreads();
    tmp[t] += v;
    __syncthreads();
  }
  incl[i] = tmp[t];
  if (t==1023) bsum[blockIdx.x] = tmp[1023];
}

__global__ void k_scan2(int* __restrict__ bsum){   // 1 block, 64 threads
  __shared__ int tmp[64];
  int t = threadIdx.x;
  tmp[t] = bsum[t];
  __syncthreads();
  for (int o=1;o<64;o<<=1){
    int v = (t>=o) ? tmp[t-o] : 0;
    __syncthreads();
    tmp[t] += v;
    __syncthreads();
  }
  bsum[t] = tmp[t];
}

__global__ void k_scan3(const int* __restrict__ incl, const int* __restrict__ bsum,
                        const int* __restrict__ deg, int* __restrict__ row_ptr){
  int i = blockIdx.x*blockDim.x + threadIdx.x;
  if (i >= NN) return;
  int b = i >> 10;
  int off = (b>0) ? bsum[b-1] : 0;
  row_ptr[i] = incl[i] - deg[i] + off;   // exclusive prefix
}

__global__ void k_la(const float* __restrict__ ssum, const int* __restrict__ deg,
                     float* __restrict__ la){
  int n = blockIdx.x*blockDim.x + threadIdx.x;
  if (n < NN) la[n] = ssum[n] / fmaxf((float)deg[n], 1.f);
}

__global__ void k_fill(const int* __restrict__ ei, const float* __restrict__ ea,
                       const int* __restrict__ row_ptr, int* __restrict__ cursor,
                       int* __restrict__ esrc, float* __restrict__ eattr){
  int e = blockIdx.x*blockDim.x + threadIdx.x;
  if (e >= ETOT) return;
  int g = e / EPG;
  int src = ei[e*2]   + g*NPG_;
  int dst = ei[e*2+1] + g*NPG_;
  int slot = atomicAdd(&cursor[dst], 1);
  int p = row_ptr[dst] + slot;
  esrc[p]  = src;
  eattr[p] = ea[e];
}

// ---------------- coefE[h] = sum_c We[h*64+c]*ae[h*64+c] ----------------
__global__ __launch_bounds__(512) void k_coef(const float* __restrict__ We,
                                              const float* __restrict__ ae,
                                              float* __restrict__ coef){
  int tid = threadIdx.x;                 // 8 waves, wave per head
  float v = We[tid]*ae[tid];
  #pragma unroll
  for (int o=32;o>0;o>>=1) v += __shfl_down(v, o);
  if ((tid & 63) == 0) coef[tid>>6] = v;
}

// ---------------- layer1 linear (K=3) ----------------
__global__ void k_lin1(const float* __restrict__ x, const float* __restrict__ W,
                       bf16* __restrict__ xs){
  int idx = blockIdx.x*blockDim.x + threadIdx.x;
  if (idx >= NN*FDIM) return;
  int n = idx >> 9, f = idx & 511;
  const float* xr = x + n*3;
  xs[idx] = __float2bfloat16(xr[0]*W[f] + xr[1]*W[FDIM+f] + xr[2]*W[2*FDIM+f]);
}

// ---------------- per-node attention logits ----------------
__global__ __launch_bounds__(512) void k_attn_node(const bf16* __restrict__ xs,
                                                   const float* __restrict__ a_s,
                                                   const float* __restrict__ a_d,
                                                   float* __restrict__ als,
                                                   float* __restrict__ ald){
  int n = blockIdx.x;
  int tid = threadIdx.x;                 // wave = head
  float v = __bfloat162float(xs[(size_t)n*FDIM + tid]);
  float s = v * a_s[tid];
  float d = v * a_d[tid];
  #pragma unroll
  for (int o=32;o>0;o>>=1){ s += __shfl_down(s,o); d += __shfl_down(d,o); }
  if ((tid&63)==0){ int hh = tid>>6; als[n*HEADS+hh]=s; ald[n*HEADS+hh]=d; }
}

// ---------------- fused GAT: logits + edge-softmax + aggregate + bias + relu ----------------
__global__ __launch_bounds__(512) void k_gat(const bf16* __restrict__ xs,
                                             const float* __restrict__ als,
                                             const float* __restrict__ ald,
                                             const float* __restrict__ coef,
                                             const int* __restrict__ row_ptr,
                                             const int* __restrict__ deg,
                                             const int* __restrict__ esrc,
                                             const float* __restrict__ eattr,
                                             const float* __restrict__ la,
                                             const float* __restrict__ bias,
                                             int self,
                                             bf16* __restrict__ h){
  int n = blockIdx.x;
  int f = threadIdx.x, hh = f >> 6;
  int row = row_ptr[n], d = deg[n];
  int tot = d + self;
  float aldn = ald[n*HEADS+hh];
  float ch = coef[hh];

  float m = -1e30f;
  for (int i=0;i<tot;i++){
    int s; float at;
    if (i<d){ s = esrc[row+i]; at = eattr[row+i]; }
    else    { s = n;           at = la[n]; }
    float raw = als[s*HEADS+hh] + aldn + at*ch;
    raw = raw > 0.f ? raw : NEG*raw;
    m = fmaxf(m, raw);
  }
  float ssum = 0.f, acc = 0.f;
  for (int i=0;i<tot;i++){
    int s; float at;
    if (i<d){ s = esrc[row+i]; at = eattr[row+i]; }
    else    { s = n;           at = la[n]; }
    float raw = als[s*HEADS+hh] + aldn + at*ch;
    raw = raw > 0.f ? raw : NEG*raw;
    float p = expf(raw - m);
    ssum += p;
    acc  += p * __bfloat162float(xs[(size_t)s*FDIM + f]);
  }
  float o = acc / fmaxf(ssum, 1e-16f) + bias[f];
  h[(size_t)n*FDIM + f] = __float2bfloat16(o > 0.f ? o : 0.f);
}

// ---------------- generic tiled GEMM: C[M,N] = A[M,K] @ B[K,N] (f32 accumulate) ----------------
template<typename TA, typename TC>
__global__ __launch_bounds__(256) void gemm_t(const TA* __restrict__ A,
                                              const float* __restrict__ B,
                                              TC* __restrict__ C,
                                              int M, int N, int K){
  __shared__ __align__(16) float As[16][68];
  __shared__ __align__(16) float Bs[16][68];
  const int bm = blockIdx.x * 64, bn = blockIdx.y * 64;
  const int tid = threadIdx.x;
  const int tm = (tid >> 4) << 2;
  const int tn = (tid & 15) << 2;
  float acc[4][4] = {};
  for (int k0 = 0; k0 < K; k0 += 16){
    #pragma unroll
    for (int i = tid; i < 64*16; i += 256){
      int m = i >> 4, kk = i & 15;
      As[kk][m] = to_f(A[(size_t)(bm+m)*K + k0 + kk]);
    }
    #pragma unroll
    for (int i = tid; i < 16*64; i += 256){
      int kk = i >> 6, n = i & 63;
      Bs[kk][n] = B[(size_t)(k0+kk)*N + bn + n];
    }
    __syncthreads();
    #pragma unroll
    for (int kk = 0; kk < 16; ++kk){
      float4 av = *reinterpret_cast<const float4*>(&As[kk][tm]);
      float4 bv = *reinterpret_cast<const float4*>(&Bs[kk][tn]);
      float a[4] = {av.x, av.y, av.z, av.w};
      float b[4] = {bv.x, bv.y, bv.z, bv.w};
      #pragma unroll
      for (int i=0;i<4;i++)
        #pragma unroll
        for (int j=0;j<4;j++)
          acc[i][j] += a[i]*b[j];
    }
    __syncthreads();
  }
  #pragma unroll
  for (int i=0;i<4;i++)
    #pragma unroll
    for (int j=0;j<4;j++)
      st_f(&C[(size_t)(bm+tm+i)*N + bn+tn+j], acc[i][j]);
}

// ---------------- head ----------------
__global__ __launch_bounds__(512) void k_gemb(const bf16* __restrict__ h, float* __restrict__ gemb){
  int g = blockIdx.x, f = threadIdx.x;
  float s = 0.f;
  const bf16* p = h + (size_t)g*NPG_*FDIM + f;
  #pragma unroll 8
  for (int n=0;n<NPG_;n++) s += __bfloat162float(p[(size_t)n*FDIM]);
  gemb[g*FDIM+f] = s * (1.f/NPG_);
}

__global__ void k_comb(const bf16* __restrict__ h, const float* __restrict__ gemb,
                       float* __restrict__ comb){
  int idx = blockIdx.x*blockDim.x + threadIdx.x;    // r*1024+k
  if (idx >= 1024*1024) return;
  int r = idx >> 10, k = idx & 1023;
  int g = r >> 3, a = r & 7;
  comb[idx] = (k < FDIM) ? __bfloat162float(h[(size_t)(g*NPG_ + a)*FDIM + k])
                         : gemb[g*FDIM + (k-FDIM)];
}

__global__ void k_bias_relu2(float* __restrict__ p, const float* __restrict__ b, int n){
  int idx = blockIdx.x*blockDim.x + threadIdx.x;
  if (idx < n) p[idx] = fmaxf(p[idx] + b[idx & 255], 0.f);
}

__global__ void k_fc2(const float* __restrict__ a, const float* __restrict__ w,
                      const float* __restrict__ b, float* __restrict__ out){
  int idx = blockIdx.x*blockDim.x + threadIdx.x;
  if (idx >= 2048) return;
  int r = idx >> 1, o = idx & 1;
  float acc = b[o];
  for (int k=0;k<256;k++) acc += a[r*256+k]*w[k*2+o];
  out[idx] = acc;
}

extern "C" void kernel_launch(void* const* d_in, const int* in_sizes, int n_in,
                              void* d_out, int out_size, void* d_ws, size_t ws_size,
                              hipStream_t stream)
{
  const float* x    = (const float*)d_in[0];
  const int*   ei   = (const int*)  d_in[1];
  const float* ea   = (const float*)d_in[2];
  const float* Wl[3]  = {(const float*)d_in[3],  (const float*)d_in[9],  (const float*)d_in[15]};
  const float* Bl[3]  = {(const float*)d_in[4],  (const float*)d_in[10], (const float*)d_in[16]};
  const float* ASl[3] = {(const float*)d_in[5],  (const float*)d_in[11], (const float*)d_in[17]};
  const float* ADl[3] = {(const float*)d_in[6],  (const float*)d_in[12], (const float*)d_in[18]};
  const float* WEl[3] = {(const float*)d_in[7],  (const float*)d_in[13], (const float*)d_in[19]};
  const float* AEl[3] = {(const float*)d_in[8],  (const float*)d_in[14], (const float*)d_in[20]};
  const float* FC1W = (const float*)d_in[21];
  const float* FC1B = (const float*)d_in[22];
  const float* FC2W = (const float*)d_in[23];
  const float* FC2B = (const float*)d_in[24];
  float* out = (float*)d_out;
  (void)in_sizes; (void)n_in;

  char* ws = (char*)d_ws;
  size_t off = 0;
  auto alloc = [&](size_t bytes)->char*{
    char* p = ws + off;
    off = (off + bytes + 255) & ~(size_t)255;
    return p;
  };
  bf16*  h       = (bf16*) alloc((size_t)NN*FDIM*2);    // 64 MB
  bf16*  xs      = (bf16*) alloc((size_t)NN*FDIM*2);    // 64 MB
  float* als     = (float*)alloc((size_t)NN*HEADS*4);   // 2 MB
  float* ald     = (float*)alloc((size_t)NN*HEADS*4);   // 2 MB
  float* la      = (float*)alloc((size_t)NN*4);
  float* ssum    = (float*)alloc((size_t)NN*4);
  int*   deg     = (int*)  alloc((size_t)NN*4);
  int*   cursor  = (int*)  alloc((size_t)NN*4);
  int*   row_ptr = (int*)  alloc((size_t)NN*4);
  int*   incl    = (int*)  alloc((size_t)NN*4);
  int*   bsum    = (int*)  alloc(64*4);
  int*   esrc    = (int*)  alloc((size_t)ETOT*4);
  float* eattr   = (float*)alloc((size_t)ETOT*4);
  float* coef    = (float*)alloc(3*HEADS*4);
  float* gemb    = (float*)alloc((size_t)NGRAPH*FDIM*4);
  float* comb    = (float*)alloc((size_t)1024*1024*4);
  float* fc1out  = (float*)alloc((size_t)1024*256*4);

  if (off > ws_size){
    // diagnostic: workspace too small — emit sentinel instead of faulting
    k_sentinel<<<(out_size+255)/256, 256, 0, stream>>>(out, out_size);
    return;
  }

  // ---- CSR build (shared across layers) ----
  k_zero <<<(NN+255)/256, 256, 0, stream>>>(deg, cursor, ssum);
  k_count<<<(ETOT+255)/256, 256, 0, stream>>>(ei, ea, deg, ssum);
  k_scan1<<<64, 1024, 0, stream>>>(deg, incl, bsum);
  k_scan2<<<1, 64, 0, stream>>>(bsum);
  k_scan3<<<(NN+255)/256, 256, 0, stream>>>(incl, bsum, deg, row_ptr);
  k_la   <<<(NN+255)/256, 256, 0, stream>>>(ssum, deg, la);
  k_fill <<<(ETOT+255)/256, 256, 0, stream>>>(ei, ea, row_ptr, cursor, esrc, eattr);

  for (int l=0;l<3;l++)
    k_coef<<<1, 512, 0, stream>>>(WEl[l], AEl[l], coef + l*HEADS);

  // ---- layer 1 (no self loops) ----
  k_lin1<<<(NN*FDIM+255)/256, 256, 0, stream>>>(x, Wl[0], xs);
  k_attn_node<<<NN, 512, 0, stream>>>(xs, ASl[0], ADl[0], als, ald);
  k_gat<<<NN, 512, 0, stream>>>(xs, als, ald, coef, row_ptr, deg, esrc, eattr, la, Bl[0], 0, h);

  // ---- layers 2,3 (with self loops) ----
  for (int l=1;l<3;l++){
    gemm_t<bf16,bf16><<<dim3(NN/64, FDIM/64), 256, 0, stream>>>(h, Wl[l], xs, NN, FDIM, FDIM);
    k_attn_node<<<NN, 512, 0, stream>>>(xs, ASl[l], ADl[l], als, ald);
    k_gat<<<NN, 512, 0, stream>>>(xs, als, ald, coef + l*HEADS, row_ptr, deg, esrc, eattr, la, Bl[l], 1, h);
  }

  // ---- head ----
  k_gemb<<<NGRAPH, 512, 0, stream>>>(h, gemb);
  k_comb<<<(1024*1024)/256, 256, 0, stream>>>(h, gemb, comb);
  gemm_t<float,float><<<dim3(1024/64, 256/64), 256, 0, stream>>>(comb, FC1W, fc1out, 1024, 256, 1024);
  k_bias_relu2<<<(1024*256+255)/256, 256, 0, stream>>>(fc1out, FC1B, 1024*256);
  k_fc2<<<(2048+255)/256, 256, 0, stream>>>(fc1out, FC2W, FC2B, out);
}

// Round 3
// 499.845 us; speedup vs baseline: 3.5731x; 3.5731x over previous
//
#include <hip/hip_runtime.h>
#include <hip/hip_bf16.h>
#include <math.h>

#define NGRAPH 128
#define NPG_   512
#define NN     (NGRAPH*NPG_)     // 65536 nodes
#define EPG    504
#define ETOT   (NGRAPH*EPG)      // 64512 real edges
#define HEADS  8
#define FDIM   512
#define NEG    0.2f

typedef __hip_bfloat16 bf16;
typedef __attribute__((ext_vector_type(8))) short short8;   // 8 bf16 = 4 VGPR
typedef __attribute__((ext_vector_type(4))) float f32x4;

static __device__ __forceinline__ float to_f(float v){ return v; }
static __device__ __forceinline__ float to_f(bf16 v){ return __bfloat162float(v); }
static __device__ __forceinline__ void st_f(float* p, float v){ *p = v; }
static __device__ __forceinline__ void st_f(bf16* p, float v){ *p = __float2bfloat16(v); }
static __device__ __forceinline__ float bf(short s){
  union { unsigned u; float f; } c; c.u = ((unsigned)(unsigned short)s) << 16; return c.f;
}

static __device__ __forceinline__ void gload16(void* lds, const void* g){
  __builtin_amdgcn_global_load_lds((const __attribute__((address_space(1))) void*)g,
                                   (__attribute__((address_space(3))) void*)lds, 16, 0, 0);
}

// ---------------- workspace guard ----------------
__global__ void k_sentinel(float* out, int n){
  int i = blockIdx.x*blockDim.x + threadIdx.x;
  if (i < n) out[i] = 12345.0f;
}

// ---------------- CSR build ----------------
__global__ void k_zero(int* __restrict__ deg, int* __restrict__ cursor, float* __restrict__ ssum){
  int i = blockIdx.x*blockDim.x + threadIdx.x;
  if (i < NN){ deg[i]=0; cursor[i]=0; ssum[i]=0.f; }
}

__global__ void k_count(const int* __restrict__ ei, const float* __restrict__ ea,
                        int* __restrict__ deg, float* __restrict__ ssum){
  int e = blockIdx.x*blockDim.x + threadIdx.x;
  if (e >= ETOT) return;
  int g = e / EPG;
  int dst = ei[e*2+1] + g*NPG_;
  atomicAdd(&deg[dst], 1);
  atomicAdd(&ssum[dst], ea[e]);
}

__global__ __launch_bounds__(1024) void k_scan1(const int* __restrict__ deg,
                                                int* __restrict__ incl, int* __restrict__ bsum){
  __shared__ int tmp[1024];
  int t = threadIdx.x;
  int i = blockIdx.x*1024 + t;
  tmp[t] = deg[i];
  __syncthreads();
  for (int o=1;o<1024;o<<=1){
    int v = (t>=o) ? tmp[t-o] : 0;
    __syncthreads();
    tmp[t] += v;
    __syncthreads();
  }
  incl[i] = tmp[t];
  if (t==1023) bsum[blockIdx.x] = tmp[1023];
}

__global__ void k_scan2(int* __restrict__ bsum){   // 1 block, 64 threads
  __shared__ int tmp[64];
  int t = threadIdx.x;
  tmp[t] = bsum[t];
  __syncthreads();
  for (int o=1;o<64;o<<=1){
    int v = (t>=o) ? tmp[t-o] : 0;
    __syncthreads();
    tmp[t] += v;
    __syncthreads();
  }
  bsum[t] = tmp[t];
}

__global__ void k_scan3(const int* __restrict__ incl, const int* __restrict__ bsum,
                        const int* __restrict__ deg, int* __restrict__ row_ptr){
  int i = blockIdx.x*blockDim.x + threadIdx.x;
  if (i >= NN) return;
  int b = i >> 10;
  int off = (b>0) ? bsum[b-1] : 0;
  row_ptr[i] = incl[i] - deg[i] + off;   // exclusive prefix
}

__global__ void k_la(const float* __restrict__ ssum, const int* __restrict__ deg,
                     float* __restrict__ la){
  int n = blockIdx.x*blockDim.x + threadIdx.x;
  if (n < NN) la[n] = ssum[n] / fmaxf((float)deg[n], 1.f);
}

__global__ void k_fill(const int* __restrict__ ei, const float* __restrict__ ea,
                       const int* __restrict__ row_ptr, int* __restrict__ cursor,
                       int* __restrict__ esrc, float* __restrict__ eattr){
  int e = blockIdx.x*blockDim.x + threadIdx.x;
  if (e >= ETOT) return;
  int g = e / EPG;
  int src = ei[e*2]   + g*NPG_;
  int dst = ei[e*2+1] + g*NPG_;
  int slot = atomicAdd(&cursor[dst], 1);
  int p = row_ptr[dst] + slot;
  esrc[p]  = src;
  eattr[p] = ea[e];
}

// ---------------- coefE[h] = sum_c We[h*64+c]*ae[h*64+c] ----------------
__global__ __launch_bounds__(512) void k_coef(const float* __restrict__ We,
                                              const float* __restrict__ ae,
                                              float* __restrict__ coef){
  int tid = threadIdx.x;                 // 8 waves, wave per head
  float v = We[tid]*ae[tid];
  #pragma unroll
  for (int o=32;o>0;o>>=1) v += __shfl_down(v, o);
  if ((tid & 63) == 0) coef[tid>>6] = v;
}

// ---------------- W -> transposed bf16 hi/lo split:  Wt[n][k] ----------------
__global__ void k_wsplit(const float* __restrict__ W, bf16* __restrict__ hi,
                         bf16* __restrict__ lo){
  int idx = blockIdx.x*blockDim.x + threadIdx.x;     // idx = n*512 + k
  if (idx >= FDIM*FDIM) return;
  int n = idx >> 9, k = idx & 511;
  float w = W[k*FDIM + n];                           // transposed read (L2-resident 1MB)
  bf16 h = __float2bfloat16(w);
  float rem = w - __bfloat162float(h);
  hi[idx] = h;
  lo[idx] = __float2bfloat16(rem);
}

// ---------------- layer1 linear (K=3), vectorized ----------------
__global__ __launch_bounds__(256) void k_lin1(const float* __restrict__ x,
                                              const float* __restrict__ W,
                                              bf16* __restrict__ xs){
  int idx = blockIdx.x*blockDim.x + threadIdx.x;     // n*64 + c
  if (idx >= NN*64) return;
  int n = idx >> 6, f0 = (idx & 63) << 3;
  const float* xr = x + n*3;
  float x0 = xr[0], x1 = xr[1], x2 = xr[2];
  short8 r;
  #pragma unroll
  for (int j=0;j<8;j++){
    float v = x0*W[f0+j] + x1*W[FDIM+f0+j] + x2*W[2*FDIM+f0+j];
    bf16 b = __float2bfloat16(v);
    r[j] = *(short*)&b;
  }
  ((short8*)xs)[idx] = r;
}

// ---------------- per-node attention logits: wave per node ----------------
__global__ __launch_bounds__(256) void k_attn_node(const bf16* __restrict__ xs,
                                                   const float* __restrict__ a_s,
                                                   const float* __restrict__ a_d,
                                                   float* __restrict__ als,
                                                   float* __restrict__ ald){
  int n = blockIdx.x*4 + (threadIdx.x >> 6);
  int lane = threadIdx.x & 63;
  short8 v = ((const short8*)(xs + (size_t)n*FDIM))[lane];
  const float4* as4 = (const float4*)a_s;
  const float4* ad4 = (const float4*)a_d;
  float4 sa = as4[lane*2], sb = as4[lane*2+1];
  float4 da = ad4[lane*2], db = ad4[lane*2+1];
  float s = bf(v[0])*sa.x + bf(v[1])*sa.y + bf(v[2])*sa.z + bf(v[3])*sa.w
          + bf(v[4])*sb.x + bf(v[5])*sb.y + bf(v[6])*sb.z + bf(v[7])*sb.w;
  float d = bf(v[0])*da.x + bf(v[1])*da.y + bf(v[2])*da.z + bf(v[3])*da.w
          + bf(v[4])*db.x + bf(v[5])*db.y + bf(v[6])*db.z + bf(v[7])*db.w;
  #pragma unroll
  for (int o=1;o<8;o<<=1){ s += __shfl_xor(s, o); d += __shfl_xor(d, o); }
  if ((lane & 7) == 0){
    int hh = lane >> 3;
    als[n*HEADS+hh] = s;
    ald[n*HEADS+hh] = d;
  }
}

// ---------------- fused GAT: wave per node, lane = 8 features ----------------
__global__ __launch_bounds__(256) void k_gat(const bf16* __restrict__ xs,
                                             const float* __restrict__ als,
                                             const float* __restrict__ ald,
                                             const float* __restrict__ coef,
                                             const int* __restrict__ row_ptr,
                                             const int* __restrict__ deg,
                                             const int* __restrict__ esrc,
                                             const float* __restrict__ eattr,
                                             const float* __restrict__ la,
                                             const float* __restrict__ bias,
                                             int self,
                                             bf16* __restrict__ h){
  int n = blockIdx.x*4 + (threadIdx.x >> 6);
  int lane = threadIdx.x & 63;
  int hh = lane >> 3;                    // head of my 8 features
  int row = row_ptr[n], d = deg[n];
  int tot = d + self;
  float aldn = ald[n*HEADS+hh];
  float ch = coef[hh];
  float lan = la[n];

  float m = -1e30f;
  for (int i=0;i<tot;i++){
    int s; float at;
    if (i<d){ s = esrc[row+i]; at = eattr[row+i]; }
    else    { s = n;           at = lan; }
    float raw = als[s*HEADS+hh] + aldn + at*ch;
    raw = raw > 0.f ? raw : NEG*raw;
    m = fmaxf(m, raw);
  }
  float ssum = 0.f;
  float acc[8] = {};
  for (int i=0;i<tot;i++){
    int s; float at;
    if (i<d){ s = esrc[row+i]; at = eattr[row+i]; }
    else    { s = n;           at = lan; }
    float raw = als[s*HEADS+hh] + aldn + at*ch;
    raw = raw > 0.f ? raw : NEG*raw;
    float p = expf(raw - m);
    ssum += p;
    short8 v = ((const short8*)(xs + (size_t)s*FDIM))[lane];
    #pragma unroll
    for (int j=0;j<8;j++) acc[j] += p * bf(v[j]);
  }
  float inv = 1.f / fmaxf(ssum, 1e-16f);
  const float4* b4 = (const float4*)bias;
  float4 ba = b4[lane*2], bb = b4[lane*2+1];
  float bias8[8] = {ba.x,ba.y,ba.z,ba.w,bb.x,bb.y,bb.z,bb.w};
  short8 r;
  #pragma unroll
  for (int j=0;j<8;j++){
    float o = acc[j]*inv + bias8[j];
    bf16 b = __float2bfloat16(o > 0.f ? o : 0.f);
    r[j] = *(short*)&b;
  }
  ((short8*)(h + (size_t)n*FDIM))[lane] = r;
}

// ---------------- MFMA GEMM: C[M,N](bf16) = A[M,K](bf16) @ (Whi+Wlo)^T ----------------
// Whi/Wlo are [N][K] bf16 (pre-transposed). 128x128 tile, BK=64, 4 waves.
// LDS XOR swizzle on 16B granules: stored g' = g ^ (row&7); staged via
// inverse-swizzled global source so global_load_lds dest stays linear (m201 pattern).
__global__ __launch_bounds__(256) void gemm_mfma(const bf16* __restrict__ A,
                                                 const bf16* __restrict__ Whi,
                                                 const bf16* __restrict__ Wlo,
                                                 bf16* __restrict__ C,
                                                 int M, int N, int K){
  __shared__ short As[128*64];
  __shared__ short Bh[128*64];
  __shared__ short Bl[128*64];
  const int bm = blockIdx.x*128, bn = blockIdx.y*128;
  const int tid = threadIdx.x;
  const int lane = tid & 63;
  const int w = tid >> 6;
  const int wm = (w >> 1)*64, wn = (w & 1)*64;
  const int lr = lane & 15;
  const int lk = lane >> 4;

  f32x4 acc[4][4] = {};

  for (int k0 = 0; k0 < K; k0 += 64){
    // ---- stage 3 tiles (A, Bhi, Blo), 4 issues each ----
    #pragma unroll
    for (int is = 0; is < 4; ++is){
      int i = is*256 + tid;            // granule id: row r, granule g
      int r = i >> 3, g = i & 7;
      int gs = g ^ (r & 7);            // inverse swizzle on source
      gload16(&As[i*8], A   + (size_t)(bm+r)*K + k0 + gs*8);
      gload16(&Bh[i*8], Whi + (size_t)(bn+r)*K + k0 + gs*8);
      gload16(&Bl[i*8], Wlo + (size_t)(bn+r)*K + k0 + gs*8);
    }
    __syncthreads();
    #pragma unroll
    for (int kk = 0; kk < 2; ++kk){
      short8 af[4], bhf[4], blf[4];
      #pragma unroll
      for (int mi=0; mi<4; ++mi){
        int row = wm + mi*16 + lr;
        int g = (kk*4 + lk) ^ (row & 7);
        af[mi] = *(const short8*)&As[row*64 + g*8];
      }
      #pragma unroll
      for (int ni=0; ni<4; ++ni){
        int row = wn + ni*16 + lr;
        int g = (kk*4 + lk) ^ (row & 7);
        bhf[ni] = *(const short8*)&Bh[row*64 + g*8];
        blf[ni] = *(const short8*)&Bl[row*64 + g*8];
      }
      #pragma unroll
      for (int mi=0; mi<4; ++mi)
        #pragma unroll
        for (int ni=0; ni<4; ++ni){
          acc[mi][ni] = __builtin_amdgcn_mfma_f32_16x16x32_bf16(af[mi], bhf[ni], acc[mi][ni], 0,0,0);
          acc[mi][ni] = __builtin_amdgcn_mfma_f32_16x16x32_bf16(af[mi], blf[ni], acc[mi][ni], 0,0,0);
        }
    }
    __syncthreads();
  }

  // epilogue: col = lane&15, row = (lane>>4)*4 + reg   (m89 layout)
  #pragma unroll
  for (int mi=0; mi<4; ++mi)
    #pragma unroll
    for (int ni=0; ni<4; ++ni){
      int col = bn + wn + ni*16 + lr;
      #pragma unroll
      for (int r=0; r<4; ++r){
        int rowg = bm + wm + mi*16 + lk*4 + r;
        C[(size_t)rowg*N + col] = __float2bfloat16(acc[mi][ni][r]);
      }
    }
}

// ---------------- head ----------------
__global__ __launch_bounds__(512) void k_gemb1(const bf16* __restrict__ h, float* __restrict__ pgemb){
  int g = blockIdx.x >> 3, s = blockIdx.x & 7;
  int f = threadIdx.x;
  float acc = 0.f;
  const bf16* p = h + ((size_t)(g*NPG_ + s*64))*FDIM + f;
  #pragma unroll 8
  for (int n=0;n<64;n++) acc += __bfloat162float(p[(size_t)n*FDIM]);
  pgemb[(size_t)blockIdx.x*FDIM + f] = acc;
}

__global__ __launch_bounds__(512) void k_gemb2(const float* __restrict__ pgemb, float* __restrict__ gemb){
  int g = blockIdx.x, f = threadIdx.x;
  float s = 0.f;
  #pragma unroll
  for (int c=0;c<8;c++) s += pgemb[(size_t)(g*8+c)*FDIM + f];
  gemb[g*FDIM+f] = s * (1.f/NPG_);
}

__global__ void k_comb(const bf16* __restrict__ h, const float* __restrict__ gemb,
                       float* __restrict__ comb){
  int idx = blockIdx.x*blockDim.x + threadIdx.x;    // r*1024+k
  if (idx >= 1024*1024) return;
  int r = idx >> 10, k = idx & 1023;
  int g = r >> 3, a = r & 7;
  comb[idx] = (k < FDIM) ? __bfloat162float(h[(size_t)(g*NPG_ + a)*FDIM + k])
                         : gemb[g*FDIM + (k-FDIM)];
}

// ---------------- generic f32 tiled GEMM (for FC1) ----------------
template<typename TA, typename TC>
__global__ __launch_bounds__(256) void gemm_t(const TA* __restrict__ A,
                                              const float* __restrict__ B,
                                              TC* __restrict__ C,
                                              int M, int N, int K){
  __shared__ __align__(16) float As[16][68];
  __shared__ __align__(16) float Bs[16][68];
  const int bm = blockIdx.x * 64, bn = blockIdx.y * 64;
  const int tid = threadIdx.x;
  const int tm = (tid >> 4) << 2;
  const int tn = (tid & 15) << 2;
  float acc[4][4] = {};
  for (int k0 = 0; k0 < K; k0 += 16){
    #pragma unroll
    for (int i = tid; i < 64*16; i += 256){
      int m = i >> 4, kk = i & 15;
      As[kk][m] = to_f(A[(size_t)(bm+m)*K + k0 + kk]);
    }
    #pragma unroll
    for (int i = tid; i < 16*64; i += 256){
      int kk = i >> 6, n = i & 63;
      Bs[kk][n] = B[(size_t)(k0+kk)*N + bn + n];
    }
    __syncthreads();
    #pragma unroll
    for (int kk = 0; kk < 16; ++kk){
      float4 av = *reinterpret_cast<const float4*>(&As[kk][tm]);
      float4 bv = *reinterpret_cast<const float4*>(&Bs[kk][tn]);
      float a[4] = {av.x, av.y, av.z, av.w};
      float b[4] = {bv.x, bv.y, bv.z, bv.w};
      #pragma unroll
      for (int i=0;i<4;i++)
        #pragma unroll
        for (int j=0;j<4;j++)
          acc[i][j] += a[i]*b[j];
    }
    __syncthreads();
  }
  #pragma unroll
  for (int i=0;i<4;i++)
    #pragma unroll
    for (int j=0;j<4;j++)
      st_f(&C[(size_t)(bm+tm+i)*N + bn+tn+j], acc[i][j]);
}

__global__ void k_bias_relu2(float* __restrict__ p, const float* __restrict__ b, int n){
  int idx = blockIdx.x*blockDim.x + threadIdx.x;
  if (idx < n) p[idx] = fmaxf(p[idx] + b[idx & 255], 0.f);
}

__global__ void k_fc2(const float* __restrict__ a, const float* __restrict__ w,
                      const float* __restrict__ b, float* __restrict__ out){
  int idx = blockIdx.x*blockDim.x + threadIdx.x;
  if (idx >= 2048) return;
  int r = idx >> 1, o = idx & 1;
  float acc = b[o];
  for (int k=0;k<256;k++) acc += a[r*256+k]*w[k*2+o];
  out[idx] = acc;
}

extern "C" void kernel_launch(void* const* d_in, const int* in_sizes, int n_in,
                              void* d_out, int out_size, void* d_ws, size_t ws_size,
                              hipStream_t stream)
{
  const float* x    = (const float*)d_in[0];
  const int*   ei   = (const int*)  d_in[1];
  const float* ea   = (const float*)d_in[2];
  const float* Wl[3]  = {(const float*)d_in[3],  (const float*)d_in[9],  (const float*)d_in[15]};
  const float* Bl[3]  = {(const float*)d_in[4],  (const float*)d_in[10], (const float*)d_in[16]};
  const float* ASl[3] = {(const float*)d_in[5],  (const float*)d_in[11], (const float*)d_in[17]};
  const float* ADl[3] = {(const float*)d_in[6],  (const float*)d_in[12], (const float*)d_in[18]};
  const float* WEl[3] = {(const float*)d_in[7],  (const float*)d_in[13], (const float*)d_in[19]};
  const float* AEl[3] = {(const float*)d_in[8],  (const float*)d_in[14], (const float*)d_in[20]};
  const float* FC1W = (const float*)d_in[21];
  const float* FC1B = (const float*)d_in[22];
  const float* FC2W = (const float*)d_in[23];
  const float* FC2B = (const float*)d_in[24];
  float* out = (float*)d_out;
  (void)in_sizes; (void)n_in;

  char* ws = (char*)d_ws;
  size_t off = 0;
  auto alloc = [&](size_t bytes)->char*{
    char* p = ws + off;
    off = (off + bytes + 255) & ~(size_t)255;
    return p;
  };
  bf16*  h       = (bf16*) alloc((size_t)NN*FDIM*2);    // 64 MB
  bf16*  xs      = (bf16*) alloc((size_t)NN*FDIM*2);    // 64 MB
  float* als     = (float*)alloc((size_t)NN*HEADS*4);   // 2 MB
  float* ald     = (float*)alloc((size_t)NN*HEADS*4);   // 2 MB
  float* la      = (float*)alloc((size_t)NN*4);
  float* ssum    = (float*)alloc((size_t)NN*4);
  int*   deg     = (int*)  alloc((size_t)NN*4);
  int*   cursor  = (int*)  alloc((size_t)NN*4);
  int*   row_ptr = (int*)  alloc((size_t)NN*4);
  int*   incl    = (int*)  alloc((size_t)NN*4);
  int*   bsum    = (int*)  alloc(64*4);
  int*   esrc    = (int*)  alloc((size_t)ETOT*4);
  float* eattr   = (float*)alloc((size_t)ETOT*4);
  float* coef    = (float*)alloc(3*HEADS*4);
  bf16*  whi     = (bf16*) alloc((size_t)2*FDIM*FDIM*2);  // layers 2,3 hi
  bf16*  wlo     = (bf16*) alloc((size_t)2*FDIM*FDIM*2);  // layers 2,3 lo
  float* gemb    = (float*)alloc((size_t)NGRAPH*FDIM*4);
  float* pgemb   = (float*)alloc((size_t)NGRAPH*8*FDIM*4);
  float* comb    = (float*)alloc((size_t)1024*1024*4);
  float* fc1out  = (float*)alloc((size_t)1024*256*4);

  if (off > ws_size){
    k_sentinel<<<(out_size+255)/256, 256, 0, stream>>>(out, out_size);
    return;
  }

  // ---- CSR build (shared across layers) ----
  k_zero <<<(NN+255)/256, 256, 0, stream>>>(deg, cursor, ssum);
  k_count<<<(ETOT+255)/256, 256, 0, stream>>>(ei, ea, deg, ssum);
  k_scan1<<<64, 1024, 0, stream>>>(deg, incl, bsum);
  k_scan2<<<1, 64, 0, stream>>>(bsum);
  k_scan3<<<(NN+255)/256, 256, 0, stream>>>(incl, bsum, deg, row_ptr);
  k_la   <<<(NN+255)/256, 256, 0, stream>>>(ssum, deg, la);
  k_fill <<<(ETOT+255)/256, 256, 0, stream>>>(ei, ea, row_ptr, cursor, esrc, eattr);

  for (int l=0;l<3;l++)
    k_coef<<<1, 512, 0, stream>>>(WEl[l], AEl[l], coef + l*HEADS);
  for (int l=1;l<3;l++)
    k_wsplit<<<(FDIM*FDIM+255)/256, 256, 0, stream>>>(Wl[l],
        whi + (size_t)(l-1)*FDIM*FDIM, wlo + (size_t)(l-1)*FDIM*FDIM);

  // ---- layer 1 (no self loops) ----
  k_lin1<<<(NN*64+255)/256, 256, 0, stream>>>(x, Wl[0], xs);
  k_attn_node<<<NN/4, 256, 0, stream>>>(xs, ASl[0], ADl[0], als, ald);
  k_gat<<<NN/4, 256, 0, stream>>>(xs, als, ald, coef, row_ptr, deg, esrc, eattr, la, Bl[0], 0, h);

  // ---- layers 2,3 (with self loops) ----
  for (int l=1;l<3;l++){
    gemm_mfma<<<dim3(NN/128, FDIM/128), 256, 0, stream>>>(h,
        whi + (size_t)(l-1)*FDIM*FDIM, wlo + (size_t)(l-1)*FDIM*FDIM, xs, NN, FDIM, FDIM);
    k_attn_node<<<NN/4, 256, 0, stream>>>(xs, ASl[l], ADl[l], als, ald);
    k_gat<<<NN/4, 256, 0, stream>>>(xs, als, ald, coef + l*HEADS, row_ptr, deg, esrc, eattr, la, Bl[l], 1, h);
  }

  // ---- head ----
  k_gemb1<<<NGRAPH*8, 512, 0, stream>>>(h, pgemb);
  k_gemb2<<<NGRAPH, 512, 0, stream>>>(pgemb, gemb);
  k_comb<<<(1024*1024)/256, 256, 0, stream>>>(h, gemb, comb);
  gemm_t<float,float><<<dim3(1024/64, 256/64), 256, 0, stream>>>(comb, FC1W, fc1out, 1024, 256, 1024);
  k_bias_relu2<<<(1024*256+255)/256, 256, 0, stream>>>(fc1out, FC1B, 1024*256);
  k_fc2<<<(2048+255)/256, 256, 0, stream>>>(fc1out, FC2W, FC2B, out);
}

// Round 4
// 381.317 us; speedup vs baseline: 4.6838x; 1.3108x over previous
//
#include <hip/hip_runtime.h>
#include <hip/hip_bf16.h>
#include <math.h>

#define NGRAPH 128
#define NPG_   512
#define NN     (NGRAPH*NPG_)     // 65536 nodes
#define EPG    504
#define ETOT   (NGRAPH*EPG)      // 64512 real edges
#define HEADS  8
#define FDIM   512
#define NEG    0.2f

typedef __hip_bfloat16 bf16;
typedef __attribute__((ext_vector_type(8))) short short8;   // 8 bf16 = 4 VGPR
typedef __attribute__((ext_vector_type(4))) float f32x4;

static __device__ __forceinline__ float bf(short s){
  union { unsigned u; float f; } c; c.u = ((unsigned)(unsigned short)s) << 16; return c.f;
}

static __device__ __forceinline__ void gload16(void* lds, const void* g){
  __builtin_amdgcn_global_load_lds((const __attribute__((address_space(1))) void*)g,
                                   (__attribute__((address_space(3))) void*)lds, 16, 0, 0);
}

// ---------------- workspace guard ----------------
__global__ void k_sentinel(float* out, int n){
  int i = blockIdx.x*blockDim.x + threadIdx.x;
  if (i < n) out[i] = 12345.0f;
}

// ---------------- CSR build ----------------
__global__ void k_zero(int* __restrict__ deg, int* __restrict__ cursor, float* __restrict__ ssum){
  int i = blockIdx.x*blockDim.x + threadIdx.x;
  if (i < NN){ deg[i]=0; cursor[i]=0; ssum[i]=0.f; }
}

__global__ void k_count(const int* __restrict__ ei, const float* __restrict__ ea,
                        int* __restrict__ deg, float* __restrict__ ssum){
  int e = blockIdx.x*blockDim.x + threadIdx.x;
  if (e >= ETOT) return;
  int g = e / EPG;
  int dst = ei[e*2+1] + g*NPG_;
  atomicAdd(&deg[dst], 1);
  atomicAdd(&ssum[dst], ea[e]);
}

__global__ __launch_bounds__(1024) void k_scan1(const int* __restrict__ deg,
                                                int* __restrict__ incl, int* __restrict__ bsum){
  __shared__ int tmp[1024];
  int t = threadIdx.x;
  int i = blockIdx.x*1024 + t;
  tmp[t] = deg[i];
  __syncthreads();
  for (int o=1;o<1024;o<<=1){
    int v = (t>=o) ? tmp[t-o] : 0;
    __syncthreads();
    tmp[t] += v;
    __syncthreads();
  }
  incl[i] = tmp[t];
  if (t==1023) bsum[blockIdx.x] = tmp[1023];
}

__global__ void k_scan2(int* __restrict__ bsum){   // 1 block, 64 threads
  __shared__ int tmp[64];
  int t = threadIdx.x;
  tmp[t] = bsum[t];
  __syncthreads();
  for (int o=1;o<64;o<<=1){
    int v = (t>=o) ? tmp[t-o] : 0;
    __syncthreads();
    tmp[t] += v;
    __syncthreads();
  }
  bsum[t] = tmp[t];
}

__global__ void k_scan3(const int* __restrict__ incl, const int* __restrict__ bsum,
                        const int* __restrict__ deg, int* __restrict__ row_ptr,
                        const float* __restrict__ ssum, float* __restrict__ la){
  int i = blockIdx.x*blockDim.x + threadIdx.x;
  if (i >= NN) return;
  int b = i >> 10;
  int off = (b>0) ? bsum[b-1] : 0;
  row_ptr[i] = incl[i] - deg[i] + off;   // exclusive prefix
  la[i] = ssum[i] / fmaxf((float)deg[i], 1.f);
}

__global__ void k_fill(const int* __restrict__ ei, const float* __restrict__ ea,
                       const int* __restrict__ row_ptr, int* __restrict__ cursor,
                       int* __restrict__ esrc, float* __restrict__ eattr){
  int e = blockIdx.x*blockDim.x + threadIdx.x;
  if (e >= ETOT) return;
  int g = e / EPG;
  int src = ei[e*2]   + g*NPG_;
  int dst = ei[e*2+1] + g*NPG_;
  int slot = atomicAdd(&cursor[dst], 1);
  int p = row_ptr[dst] + slot;
  esrc[p]  = src;
  eattr[p] = ea[e];
}

// ---------------- coefE[h] = sum_c We[h*64+c]*ae[h*64+c], 3 layers in one ----------------
__global__ __launch_bounds__(512) void k_coef3(const float* __restrict__ We0, const float* __restrict__ ae0,
                                               const float* __restrict__ We1, const float* __restrict__ ae1,
                                               const float* __restrict__ We2, const float* __restrict__ ae2,
                                               float* __restrict__ coef){
  int l = blockIdx.x;
  const float* We = l==0 ? We0 : (l==1 ? We1 : We2);
  const float* ae = l==0 ? ae0 : (l==1 ? ae1 : ae2);
  int tid = threadIdx.x;                 // 8 waves, wave per head
  float v = We[tid]*ae[tid];
  #pragma unroll
  for (int o=32;o>0;o>>=1) v += __shfl_down(v, o);
  if ((tid & 63) == 0) coef[l*HEADS + (tid>>6)] = v;
}

// ---------------- W -> transposed bf16 hi/lo split: Wt[n][k], layers 2,3 ----------------
__global__ void k_wsplit(const float* __restrict__ W1, const float* __restrict__ W2,
                         bf16* __restrict__ hi, bf16* __restrict__ lo){
  int idx = blockIdx.x*blockDim.x + threadIdx.x;     // l*256K + n*512 + k
  if (idx >= 2*FDIM*FDIM) return;
  int l = idx >> 18;
  int r = idx & (FDIM*FDIM-1);
  int n = r >> 9, k = r & 511;
  const float* W = l ? W2 : W1;
  float w = W[k*FDIM + n];                           // transposed read (L2-resident 1MB)
  bf16 h = __float2bfloat16(w);
  float rem = w - __bfloat162float(h);
  hi[idx] = h;
  lo[idx] = __float2bfloat16(rem);
}

// ---------------- layer1 linear (K=3) + attention logits fused: wave per node ----------------
__global__ __launch_bounds__(256) void k_lin1_attn(const float* __restrict__ x,
                                                   const float* __restrict__ W,
                                                   const float* __restrict__ a_s,
                                                   const float* __restrict__ a_d,
                                                   bf16* __restrict__ xs,
                                                   float* __restrict__ als,
                                                   float* __restrict__ ald){
  int n = blockIdx.x*4 + (threadIdx.x >> 6);
  int lane = threadIdx.x & 63;
  int f0 = lane << 3;
  const float* xr = x + n*3;
  float x0 = xr[0], x1 = xr[1], x2 = xr[2];
  float v[8];
  short8 r;
  #pragma unroll
  for (int j=0;j<8;j++){
    v[j] = x0*W[f0+j] + x1*W[FDIM+f0+j] + x2*W[2*FDIM+f0+j];
    bf16 b = __float2bfloat16(v[j]);
    r[j] = *(short*)&b;
  }
  ((short8*)(xs + (size_t)n*FDIM))[lane] = r;
  const float4* as4 = (const float4*)(a_s + f0);
  const float4* ad4 = (const float4*)(a_d + f0);
  float4 sa = as4[0], sb = as4[1];
  float4 da = ad4[0], db = ad4[1];
  float s = v[0]*sa.x + v[1]*sa.y + v[2]*sa.z + v[3]*sa.w
          + v[4]*sb.x + v[5]*sb.y + v[6]*sb.z + v[7]*sb.w;
  float d = v[0]*da.x + v[1]*da.y + v[2]*da.z + v[3]*da.w
          + v[4]*db.x + v[5]*db.y + v[6]*db.z + v[7]*db.w;
  #pragma unroll
  for (int o=1;o<8;o<<=1){ s += __shfl_xor(s, o); d += __shfl_xor(d, o); }
  if ((lane & 7) == 0){
    int hh = lane >> 3;
    als[n*HEADS+hh] = s;
    ald[n*HEADS+hh] = d;
  }
}

// ---------------- per-node attention logits: wave per node (layers 2,3) ----------------
__global__ __launch_bounds__(256) void k_attn_node(const bf16* __restrict__ xs,
                                                   const float* __restrict__ a_s,
                                                   const float* __restrict__ a_d,
                                                   float* __restrict__ als,
                                                   float* __restrict__ ald){
  int n = blockIdx.x*4 + (threadIdx.x >> 6);
  int lane = threadIdx.x & 63;
  short8 v = ((const short8*)(xs + (size_t)n*FDIM))[lane];
  const float4* as4 = (const float4*)a_s;
  const float4* ad4 = (const float4*)a_d;
  float4 sa = as4[lane*2], sb = as4[lane*2+1];
  float4 da = ad4[lane*2], db = ad4[lane*2+1];
  float s = bf(v[0])*sa.x + bf(v[1])*sa.y + bf(v[2])*sa.z + bf(v[3])*sa.w
          + bf(v[4])*sb.x + bf(v[5])*sb.y + bf(v[6])*sb.z + bf(v[7])*sb.w;
  float d = bf(v[0])*da.x + bf(v[1])*da.y + bf(v[2])*da.z + bf(v[3])*da.w
          + bf(v[4])*db.x + bf(v[5])*db.y + bf(v[6])*db.z + bf(v[7])*db.w;
  #pragma unroll
  for (int o=1;o<8;o<<=1){ s += __shfl_xor(s, o); d += __shfl_xor(d, o); }
  if ((lane & 7) == 0){
    int hh = lane >> 3;
    als[n*HEADS+hh] = s;
    ald[n*HEADS+hh] = d;
  }
}

// ---------------- fused GAT: wave per node, lane = 8 features; XCD-swizzled ----------------
__global__ __launch_bounds__(256) void k_gat(const bf16* __restrict__ xs,
                                             const float* __restrict__ als,
                                             const float* __restrict__ ald,
                                             const float* __restrict__ coef,
                                             const int* __restrict__ row_ptr,
                                             const int* __restrict__ deg,
                                             const int* __restrict__ esrc,
                                             const float* __restrict__ eattr,
                                             const float* __restrict__ la,
                                             const float* __restrict__ bias,
                                             int self,
                                             bf16* __restrict__ h){
  // XCD swizzle: contiguous chunk per XCD so each XCD's L2 sees few graphs at a time
  int nwg = gridDim.x;                   // 16384, %8 == 0
  int cpx = nwg >> 3;
  int bid = blockIdx.x;
  int swz = (bid & 7)*cpx + (bid >> 3);
  int n = swz*4 + (threadIdx.x >> 6);
  int lane = threadIdx.x & 63;
  int hh = lane >> 3;                    // head of my 8 features
  int row = row_ptr[n], d = deg[n];
  int tot = d + self;
  float aldn = ald[n*HEADS+hh];
  float ch = coef[hh];
  float lan = la[n];

  float m = -1e30f;
  for (int i=0;i<tot;i++){
    int s; float at;
    if (i<d){ s = esrc[row+i]; at = eattr[row+i]; }
    else    { s = n;           at = lan; }
    float raw = als[s*HEADS+hh] + aldn + at*ch;
    raw = raw > 0.f ? raw : NEG*raw;
    m = fmaxf(m, raw);
  }
  float ssum = 0.f;
  float acc[8] = {};
  for (int i=0;i<tot;i++){
    int s; float at;
    if (i<d){ s = esrc[row+i]; at = eattr[row+i]; }
    else    { s = n;           at = lan; }
    float raw = als[s*HEADS+hh] + aldn + at*ch;
    raw = raw > 0.f ? raw : NEG*raw;
    float p = expf(raw - m);
    ssum += p;
    short8 v = ((const short8*)(xs + (size_t)s*FDIM))[lane];
    #pragma unroll
    for (int j=0;j<8;j++) acc[j] += p * bf(v[j]);
  }
  float inv = 1.f / fmaxf(ssum, 1e-16f);
  const float4* b4 = (const float4*)bias;
  float4 ba = b4[lane*2], bb = b4[lane*2+1];
  float bias8[8] = {ba.x,ba.y,ba.z,ba.w,bb.x,bb.y,bb.z,bb.w};
  short8 r;
  #pragma unroll
  for (int j=0;j<8;j++){
    float o = acc[j]*inv + bias8[j];
    bf16 b = __float2bfloat16(o > 0.f ? o : 0.f);
    r[j] = *(short*)&b;
  }
  ((short8*)(h + (size_t)n*FDIM))[lane] = r;
}

// ---------------- MFMA GEMM: C[M,N](bf16) = A[M,K](bf16) @ (Whi+Wlo)^T ----------------
__global__ __launch_bounds__(256) void gemm_mfma(const bf16* __restrict__ A,
                                                 const bf16* __restrict__ Whi,
                                                 const bf16* __restrict__ Wlo,
                                                 bf16* __restrict__ C,
                                                 int M, int N, int K){
  __shared__ short As[128*64];
  __shared__ short Bh[128*64];
  __shared__ short Bl[128*64];
  const int bm = blockIdx.x*128, bn = blockIdx.y*128;
  const int tid = threadIdx.x;
  const int lane = tid & 63;
  const int w = tid >> 6;
  const int wm = (w >> 1)*64, wn = (w & 1)*64;
  const int lr = lane & 15;
  const int lk = lane >> 4;

  f32x4 acc[4][4] = {};

  for (int k0 = 0; k0 < K; k0 += 64){
    #pragma unroll
    for (int is = 0; is < 4; ++is){
      int i = is*256 + tid;            // granule id: row r, granule g
      int r = i >> 3, g = i & 7;
      int gs = g ^ (r & 7);            // inverse swizzle on source
      gload16(&As[i*8], A   + (size_t)(bm+r)*K + k0 + gs*8);
      gload16(&Bh[i*8], Whi + (size_t)(bn+r)*K + k0 + gs*8);
      gload16(&Bl[i*8], Wlo + (size_t)(bn+r)*K + k0 + gs*8);
    }
    __syncthreads();
    #pragma unroll
    for (int kk = 0; kk < 2; ++kk){
      short8 af[4], bhf[4], blf[4];
      #pragma unroll
      for (int mi=0; mi<4; ++mi){
        int row = wm + mi*16 + lr;
        int g = (kk*4 + lk) ^ (row & 7);
        af[mi] = *(const short8*)&As[row*64 + g*8];
      }
      #pragma unroll
      for (int ni=0; ni<4; ++ni){
        int row = wn + ni*16 + lr;
        int g = (kk*4 + lk) ^ (row & 7);
        bhf[ni] = *(const short8*)&Bh[row*64 + g*8];
        blf[ni] = *(const short8*)&Bl[row*64 + g*8];
      }
      #pragma unroll
      for (int mi=0; mi<4; ++mi)
        #pragma unroll
        for (int ni=0; ni<4; ++ni){
          acc[mi][ni] = __builtin_amdgcn_mfma_f32_16x16x32_bf16(af[mi], bhf[ni], acc[mi][ni], 0,0,0);
          acc[mi][ni] = __builtin_amdgcn_mfma_f32_16x16x32_bf16(af[mi], blf[ni], acc[mi][ni], 0,0,0);
        }
    }
    __syncthreads();
  }

  // epilogue: col = lane&15, row = (lane>>4)*4 + reg   (m89 layout)
  #pragma unroll
  for (int mi=0; mi<4; ++mi)
    #pragma unroll
    for (int ni=0; ni<4; ++ni){
      int col = bn + wn + ni*16 + lr;
      #pragma unroll
      for (int r=0; r<4; ++r){
        int rowg = bm + wm + mi*16 + lk*4 + r;
        C[(size_t)rowg*N + col] = __float2bfloat16(acc[mi][ni][r]);
      }
    }
}

// ---------------- head part 1: per-64-node partial sums ----------------
__global__ __launch_bounds__(512) void k_gemb1(const bf16* __restrict__ h, float* __restrict__ pgemb){
  int g = blockIdx.x >> 3, s = blockIdx.x & 7;
  int f = threadIdx.x;
  float acc = 0.f;
  const bf16* p = h + ((size_t)(g*NPG_ + s*64))*FDIM + f;
  #pragma unroll 8
  for (int n=0;n<64;n++) acc += __bfloat162float(p[(size_t)n*FDIM]);
  pgemb[(size_t)blockIdx.x*FDIM + f] = acc;
}

// ---------------- head part 2: fused mean + FC1 + ReLU + FC2, block per graph ----------------
__global__ __launch_bounds__(256) void k_head(const bf16* __restrict__ h,
                                              const float* __restrict__ pgemb,
                                              const float* __restrict__ fc1w,
                                              const float* __restrict__ fc1b,
                                              const float* __restrict__ fc2w,
                                              const float* __restrict__ fc2b,
                                              float* __restrict__ out){
  __shared__ float ge[FDIM];        // graph embedding (mean)
  __shared__ float ag[8][FDIM];     // 8 agent rows
  __shared__ float f1[8][256];      // fc1 activations
  int g = blockIdx.x, t = threadIdx.x;

  for (int f = t; f < FDIM; f += 256){
    float s = 0.f;
    #pragma unroll
    for (int c=0;c<8;c++) s += pgemb[(size_t)(g*8+c)*FDIM + f];
    ge[f] = s * (1.f/NPG_);
  }
  for (int i = t; i < 8*64; i += 256){      // 8 rows x 64 short8
    int r = i >> 6, c = i & 63;
    short8 v = ((const short8*)(h + (size_t)(g*NPG_ + r)*FDIM))[c];
    #pragma unroll
    for (int j=0;j<8;j++) ag[r][c*8+j] = bf(v[j]);
  }
  __syncthreads();

  // FC1: thread t = output column n; graph half shared across the 8 agent rows
  float acc[8] = {};
  float gacc = 0.f;
  for (int k = 0; k < FDIM; k += 4){
    float w0 = fc1w[(k+0)*256+t];
    float w1 = fc1w[(k+1)*256+t];
    float w2 = fc1w[(k+2)*256+t];
    float w3 = fc1w[(k+3)*256+t];
    #pragma unroll
    for (int r=0;r<8;r++){
      float4 a = *(const float4*)&ag[r][k];
      acc[r] += a.x*w0 + a.y*w1 + a.z*w2 + a.w*w3;
    }
    float v0 = fc1w[(FDIM+k+0)*256+t];
    float v1 = fc1w[(FDIM+k+1)*256+t];
    float v2 = fc1w[(FDIM+k+2)*256+t];
    float v3 = fc1w[(FDIM+k+3)*256+t];
    float4 gv = *(const float4*)&ge[k];
    gacc += gv.x*v0 + gv.y*v1 + gv.z*v2 + gv.w*v3;
  }
  float b = fc1b[t];
  #pragma unroll
  for (int r=0;r<8;r++) f1[r][t] = fmaxf(acc[r] + gacc + b, 0.f);
  __syncthreads();

  // FC2: 16 outputs (8 rows x 2), 8 threads each
  if (t < 128){
    int r = t >> 4, o = (t >> 3) & 1, l = t & 7;
    float s = 0.f;
    for (int k = l; k < 256; k += 8) s += f1[r][k] * fc2w[k*2+o];
    #pragma unroll
    for (int off=4; off; off>>=1) s += __shfl_down(s, off);
    if (l == 0) out[(g*8 + r)*2 + o] = s + fc2b[o];
  }
}

extern "C" void kernel_launch(void* const* d_in, const int* in_sizes, int n_in,
                              void* d_out, int out_size, void* d_ws, size_t ws_size,
                              hipStream_t stream)
{
  const float* x    = (const float*)d_in[0];
  const int*   ei   = (const int*)  d_in[1];
  const float* ea   = (const float*)d_in[2];
  const float* Wl[3]  = {(const float*)d_in[3],  (const float*)d_in[9],  (const float*)d_in[15]};
  const float* Bl[3]  = {(const float*)d_in[4],  (const float*)d_in[10], (const float*)d_in[16]};
  const float* ASl[3] = {(const float*)d_in[5],  (const float*)d_in[11], (const float*)d_in[17]};
  const float* ADl[3] = {(const float*)d_in[6],  (const float*)d_in[12], (const float*)d_in[18]};
  const float* WEl[3] = {(const float*)d_in[7],  (const float*)d_in[13], (const float*)d_in[19]};
  const float* AEl[3] = {(const float*)d_in[8],  (const float*)d_in[14], (const float*)d_in[20]};
  const float* FC1W = (const float*)d_in[21];
  const float* FC1B = (const float*)d_in[22];
  const float* FC2W = (const float*)d_in[23];
  const float* FC2B = (const float*)d_in[24];
  float* out = (float*)d_out;
  (void)in_sizes; (void)n_in;

  char* ws = (char*)d_ws;
  size_t off = 0;
  auto alloc = [&](size_t bytes)->char*{
    char* p = ws + off;
    off = (off + bytes + 255) & ~(size_t)255;
    return p;
  };
  bf16*  h       = (bf16*) alloc((size_t)NN*FDIM*2);    // 64 MB
  bf16*  xs      = (bf16*) alloc((size_t)NN*FDIM*2);    // 64 MB
  float* als     = (float*)alloc((size_t)NN*HEADS*4);   // 2 MB
  float* ald     = (float*)alloc((size_t)NN*HEADS*4);   // 2 MB
  float* la      = (float*)alloc((size_t)NN*4);
  float* ssum    = (float*)alloc((size_t)NN*4);
  int*   deg     = (int*)  alloc((size_t)NN*4);
  int*   cursor  = (int*)  alloc((size_t)NN*4);
  int*   row_ptr = (int*)  alloc((size_t)NN*4);
  int*   incl    = (int*)  alloc((size_t)NN*4);
  int*   bsum    = (int*)  alloc(64*4);
  int*   esrc    = (int*)  alloc((size_t)ETOT*4);
  float* eattr   = (float*)alloc((size_t)ETOT*4);
  float* coef    = (float*)alloc(3*HEADS*4);
  bf16*  whi     = (bf16*) alloc((size_t)2*FDIM*FDIM*2);  // layers 2,3 hi
  bf16*  wlo     = (bf16*) alloc((size_t)2*FDIM*FDIM*2);  // layers 2,3 lo
  float* pgemb   = (float*)alloc((size_t)NGRAPH*8*FDIM*4);

  if (off > ws_size){
    k_sentinel<<<(out_size+255)/256, 256, 0, stream>>>(out, out_size);
    return;
  }

  // ---- CSR build (shared across layers) ----
  k_zero <<<(NN+255)/256, 256, 0, stream>>>(deg, cursor, ssum);
  k_count<<<(ETOT+255)/256, 256, 0, stream>>>(ei, ea, deg, ssum);
  k_scan1<<<64, 1024, 0, stream>>>(deg, incl, bsum);
  k_scan2<<<1, 64, 0, stream>>>(bsum);
  k_scan3<<<(NN+255)/256, 256, 0, stream>>>(incl, bsum, deg, row_ptr, ssum, la);
  k_fill <<<(ETOT+255)/256, 256, 0, stream>>>(ei, ea, row_ptr, cursor, esrc, eattr);

  k_coef3<<<3, 512, 0, stream>>>(WEl[0], AEl[0], WEl[1], AEl[1], WEl[2], AEl[2], coef);
  k_wsplit<<<(2*FDIM*FDIM+255)/256, 256, 0, stream>>>(Wl[1], Wl[2], whi, wlo);

  // ---- layer 1 (no self loops), linear + logits fused ----
  k_lin1_attn<<<NN/4, 256, 0, stream>>>(x, Wl[0], ASl[0], ADl[0], xs, als, ald);
  k_gat<<<NN/4, 256, 0, stream>>>(xs, als, ald, coef, row_ptr, deg, esrc, eattr, la, Bl[0], 0, h);

  // ---- layers 2,3 (with self loops) ----
  for (int l=1;l<3;l++){
    gemm_mfma<<<dim3(NN/128, FDIM/128), 256, 0, stream>>>(h,
        whi + (size_t)(l-1)*FDIM*FDIM, wlo + (size_t)(l-1)*FDIM*FDIM, xs, NN, FDIM, FDIM);
    k_attn_node<<<NN/4, 256, 0, stream>>>(xs, ASl[l], ADl[l], als, ald);
    k_gat<<<NN/4, 256, 0, stream>>>(xs, als, ald, coef + l*HEADS, row_ptr, deg, esrc, eattr, la, Bl[l], 1, h);
  }

  // ---- head ----
  k_gemb1<<<NGRAPH*8, 512, 0, stream>>>(h, pgemb);
  k_head <<<NGRAPH, 256, 0, stream>>>(h, pgemb, FC1W, FC1B, FC2W, FC2B, out);
}